// Round 1
// baseline (194.550 us; speedup 1.0000x reference)
//
#include <hip/hip_runtime.h>
#include <hip/hip_bf16.h>
#include <cstdint>
#include <cstddef>

#define BATCH   8192
#define NSAMP   8192
#define DIM     512
#define NCLASS  50000

typedef __attribute__((ext_vector_type(8))) short bf16x8;
typedef __attribute__((ext_vector_type(4))) float f32x4;

// -log(expected_count(c)) for the log-uniform sampler, in double to match the
// numpy reference (f32 log(c+2)-log(c+1) catastrophically cancels at large c).
__device__ __forceinline__ float neg_log_expected(int c) {
    double p = log1p(1.0 / (double)(c + 1)) / log((double)(NCLASS + 1));
    double e = -expm1((double)NSAMP * log1p(-p));
    return (float)(-log(e));
}

__device__ __forceinline__ unsigned short f2bf(float f) {
    __hip_bfloat16 h = __float2bfloat16(f);
    return *reinterpret_cast<unsigned short*>(&h);
}

__device__ __forceinline__ void gload_lds16(const void* g, void* l) {
    __builtin_amdgcn_global_load_lds(
        (const __attribute__((address_space(1))) void*)g,
        (__attribute__((address_space(3))) void*)l, 16, 0, 0);
}

// ---- kernel 1: inputs f32 -> bf16 (A matrix) -------------------------------
__global__ void k_convert(const float* __restrict__ in, __hip_bfloat16* __restrict__ out) {
    int t = blockIdx.x * blockDim.x + threadIdx.x;   // one float4 each, exact grid
    float4 v = reinterpret_cast<const float4*>(in)[t];
    ushort4 u;
    u.x = f2bf(v.x); u.y = f2bf(v.y); u.z = f2bf(v.z); u.w = f2bf(v.w);
    reinterpret_cast<ushort4*>(out)[t] = u;
}

// ---- kernel 2: gather kernel[sampled] -> bf16 B; adj[s] = bias - log(expected)
__global__ void k_gather(const float* __restrict__ W, const float* __restrict__ bias,
                         const int* __restrict__ sampled,
                         __hip_bfloat16* __restrict__ Bbf, float* __restrict__ adj) {
    int s   = blockIdx.x;
    int idx = sampled[s];
    const float4* src = reinterpret_cast<const float4*>(W + (size_t)idx * DIM);
    float4 v = src[threadIdx.x];                  // 128 threads x float4 = 512
    ushort4 u;
    u.x = f2bf(v.x); u.y = f2bf(v.y); u.z = f2bf(v.z); u.w = f2bf(v.w);
    reinterpret_cast<ushort4*>(Bbf + (size_t)s * DIM)[threadIdx.x] = u;
    if (threadIdx.x == 0) adj[s] = bias[idx] + neg_log_expected(idx);
}

// ---- kernel 3: true logits (wave per row), seed row_sum = exp(true_logit) ---
__global__ void k_true(const float* __restrict__ inputs, const int* __restrict__ labels,
                       const float* __restrict__ W, const float* __restrict__ bias,
                       float* __restrict__ true_logit, float* __restrict__ row_sum) {
    int gt   = blockIdx.x * blockDim.x + threadIdx.x;
    int row  = gt >> 6;
    int lane = gt & 63;
    int lbl  = labels[row];
    const float4* xi = reinterpret_cast<const float4*>(inputs + (size_t)row * DIM);
    const float4* wi = reinterpret_cast<const float4*>(W + (size_t)lbl * DIM);
    float dot = 0.f;
    #pragma unroll
    for (int j = 0; j < 2; ++j) {
        float4 a = xi[lane + j * 64];
        float4 b = wi[lane + j * 64];
        dot += a.x * b.x + a.y * b.y + a.z * b.z + a.w * b.w;
    }
    #pragma unroll
    for (int off = 32; off; off >>= 1) dot += __shfl_down(dot, off, 64);
    if (lane == 0) {
        float tl = dot + bias[lbl] + neg_log_expected(lbl);
        true_logit[row] = tl;
        row_sum[row]    = expf(tl);
    }
}

// ---- kernel 4: 8192x8192x512 bf16 GEMM + exp/mask/row-sum epilogue ----------
// m97 structure: 128x128 tile, BK=32, 4 waves (2x2), global_load_lds w=16,
// double-buffered LDS, 16x mfma_f32_16x16x32_bf16 per K-step.
__global__ __launch_bounds__(256) void k_gemm(
    const __hip_bfloat16* __restrict__ A, const __hip_bfloat16* __restrict__ B,
    const float* __restrict__ adj, const int* __restrict__ labels,
    const int* __restrict__ sampled, float* __restrict__ row_sum) {
    __shared__ alignas(16) __hip_bfloat16 Asm[2][128 * 32];
    __shared__ alignas(16) __hip_bfloat16 Bsm[2][128 * 32];

    const int tid  = threadIdx.x;
    const int wave = tid >> 6;
    const int lane = tid & 63;
    const int wr   = wave >> 1;
    const int wc   = wave & 1;

    // XCD-bijective swizzle (nwg = 4096, 4096 % 8 == 0)
    int bid = blockIdx.x;
    int wg  = (bid & 7) * 512 + (bid >> 3);
    const int brow = (wg >> 6) * 128;
    const int bcol = (wg & 63) * 128;

    const int l4  = lane >> 2;   // 0..15: row within a 16-row staging issue
    const int lm4 = lane & 3;    // 16B segment within the 64B row chunk

    f32x4 acc[4][4];
    #pragma unroll
    for (int m = 0; m < 4; ++m)
        #pragma unroll
        for (int n = 0; n < 4; ++n)
            acc[m][n] = (f32x4){0.f, 0.f, 0.f, 0.f};

    auto stage = [&](int buf, int kt) {
        #pragma unroll
        for (int i = 0; i < 2; ++i) {
            const __hip_bfloat16* gA =
                A + (size_t)(brow + wave * 32 + i * 16 + l4) * DIM + kt * 32 + lm4 * 8;
            gload_lds16(gA, &Asm[buf][(wave * 32 + i * 16) * 32]);
            const __hip_bfloat16* gB =
                B + (size_t)(bcol + wave * 32 + i * 16 + l4) * DIM + kt * 32 + lm4 * 8;
            gload_lds16(gB, &Bsm[buf][(wave * 32 + i * 16) * 32]);
        }
    };

    stage(0, 0);
    __syncthreads();

    const int rsel = lane & 15;
    const int koff = (lane >> 4) * 8;
    int cur = 0;
    for (int kt = 0; kt < DIM / 32; ++kt) {
        if (kt + 1 < DIM / 32) stage(cur ^ 1, kt + 1);
        bf16x8 a[4], b[4];
        #pragma unroll
        for (int m = 0; m < 4; ++m)
            a[m] = *reinterpret_cast<const bf16x8*>(
                &Asm[cur][(wr * 64 + m * 16 + rsel) * 32 + koff]);
        #pragma unroll
        for (int n = 0; n < 4; ++n)
            b[n] = *reinterpret_cast<const bf16x8*>(
                &Bsm[cur][(wc * 64 + n * 16 + rsel) * 32 + koff]);
        #pragma unroll
        for (int m = 0; m < 4; ++m)
            #pragma unroll
            for (int n = 0; n < 4; ++n)
                acc[m][n] = __builtin_amdgcn_mfma_f32_16x16x32_bf16(a[m], b[n], acc[m][n], 0, 0, 0);
        __syncthreads();
        cur ^= 1;
    }

    // Epilogue: logit = acc + adj[col]; mask label==sampled; exp; per-row sum.
    int   gcol[4]; float aadj[4]; int sval[4];
    #pragma unroll
    for (int n = 0; n < 4; ++n) {
        gcol[n] = bcol + wc * 64 + n * 16 + rsel;
        aadj[n] = adj[gcol[n]];
        sval[n] = sampled[gcol[n]];
    }
    #pragma unroll
    for (int m = 0; m < 4; ++m) {
        int growb = brow + wr * 64 + m * 16 + (lane >> 4) * 4;
        #pragma unroll
        for (int r = 0; r < 4; ++r) {
            int grow = growb + r;
            int lbl  = labels[grow];
            float part = 0.f;
            #pragma unroll
            for (int n = 0; n < 4; ++n) {
                float logit = acc[m][n][r] + aadj[n];
                part += (sval[n] == lbl) ? 0.f : __expf(logit);
            }
            part += __shfl_xor(part, 1, 16);
            part += __shfl_xor(part, 2, 16);
            part += __shfl_xor(part, 4, 16);
            part += __shfl_xor(part, 8, 16);
            if (rsel == 0) atomicAdd(&row_sum[grow], part);
        }
    }
}

// ---- kernel 5: loss = log(row_sum) - true_logit -----------------------------
__global__ void k_final(const float* __restrict__ row_sum,
                        const float* __restrict__ true_logit,
                        float* __restrict__ loss) {
    int i = blockIdx.x * blockDim.x + threadIdx.x;
    loss[i] = logf(row_sum[i]) - true_logit[i];
}

extern "C" void kernel_launch(void* const* d_in, const int* in_sizes, int n_in,
                              void* d_out, int out_size, void* d_ws, size_t ws_size,
                              hipStream_t stream) {
    const float* inputs  = (const float*)d_in[0];
    const int*   labels  = (const int*)d_in[1];
    const float* W       = (const float*)d_in[2];
    const float* bias    = (const float*)d_in[3];
    const int*   sampled = (const int*)d_in[4];
    float*       loss    = (float*)d_out;

    char* ws = (char*)d_ws;
    __hip_bfloat16* Abf = (__hip_bfloat16*)ws;                                  // 8 MiB
    __hip_bfloat16* Bbf = (__hip_bfloat16*)(ws + (size_t)BATCH * DIM * 2);      // 8 MiB
    float* adj        = (float*)(ws + (size_t)(BATCH + NSAMP) * DIM * 2);       // 32 KiB
    float* true_logit = adj + NSAMP;                                            // 32 KiB
    float* row_sum    = true_logit + BATCH;                                     // 32 KiB

    hipLaunchKernelGGL(k_convert, dim3((BATCH * DIM / 4) / 256), dim3(256), 0, stream,
                       inputs, Abf);
    hipLaunchKernelGGL(k_gather, dim3(NSAMP), dim3(128), 0, stream,
                       W, bias, sampled, Bbf, adj);
    hipLaunchKernelGGL(k_true, dim3(BATCH / 4), dim3(256), 0, stream,
                       inputs, labels, W, bias, true_logit, row_sum);
    hipLaunchKernelGGL(k_gemm, dim3((BATCH / 128) * (NSAMP / 128)), dim3(256), 0, stream,
                       Abf, Bbf, adj, labels, sampled, row_sum);
    hipLaunchKernelGGL(k_final, dim3(BATCH / 256), dim3(256), 0, stream,
                       row_sum, true_logit, loss);
}

// Round 2
// 147.300 us; speedup vs baseline: 1.3208x; 1.3208x over previous
//
#include <hip/hip_runtime.h>
#include <hip/hip_bf16.h>
#include <cstdint>
#include <cstddef>

#define BATCH   8192
#define NSAMP   8192
#define DIM     512
#define NCLASS  50000

typedef __attribute__((ext_vector_type(8))) short bf16x8;
typedef __attribute__((ext_vector_type(4))) float f32x4;

// -log(expected_count(c)) for the log-uniform sampler, in double to match the
// numpy reference (f32 log(c+2)-log(c+1) catastrophically cancels at large c).
__device__ __forceinline__ float neg_log_expected(int c) {
    double p = log1p(1.0 / (double)(c + 1)) / log((double)(NCLASS + 1));
    double e = -expm1((double)NSAMP * log1p(-p));
    return (float)(-log(e));
}

__device__ __forceinline__ unsigned short f2bf(float f) {
    __hip_bfloat16 h = __float2bfloat16(f);
    return *reinterpret_cast<unsigned short*>(&h);
}

__device__ __forceinline__ void gload_lds16(const void* g, void* l) {
    __builtin_amdgcn_global_load_lds(
        (const __attribute__((address_space(1))) void*)g,
        (__attribute__((address_space(3))) void*)l, 16, 0, 0);
}

// ---- kernel 1: inputs f32 -> bf16 (A matrix) -------------------------------
__global__ void k_convert(const float* __restrict__ in, __hip_bfloat16* __restrict__ out) {
    int t = blockIdx.x * blockDim.x + threadIdx.x;   // one float4 each, exact grid
    float4 v = reinterpret_cast<const float4*>(in)[t];
    ushort4 u;
    u.x = f2bf(v.x); u.y = f2bf(v.y); u.z = f2bf(v.z); u.w = f2bf(v.w);
    reinterpret_cast<ushort4*>(out)[t] = u;
}

// ---- kernel 2: gather kernel[sampled] -> bf16 B; adj[s] = bias - log(expected)
__global__ void k_gather(const float* __restrict__ W, const float* __restrict__ bias,
                         const int* __restrict__ sampled,
                         __hip_bfloat16* __restrict__ Bbf, float* __restrict__ adj) {
    int s   = blockIdx.x;
    int idx = sampled[s];
    const float4* src = reinterpret_cast<const float4*>(W + (size_t)idx * DIM);
    float4 v = src[threadIdx.x];                  // 128 threads x float4 = 512
    ushort4 u;
    u.x = f2bf(v.x); u.y = f2bf(v.y); u.z = f2bf(v.z); u.w = f2bf(v.w);
    reinterpret_cast<ushort4*>(Bbf + (size_t)s * DIM)[threadIdx.x] = u;
    if (threadIdx.x == 0) adj[s] = bias[idx] + neg_log_expected(idx);
}

// ---- kernel 3: true logits (wave per row), seed row_sum = exp(true_logit) ---
__global__ void k_true(const float* __restrict__ inputs, const int* __restrict__ labels,
                       const float* __restrict__ W, const float* __restrict__ bias,
                       float* __restrict__ true_logit, float* __restrict__ row_sum) {
    int gt   = blockIdx.x * blockDim.x + threadIdx.x;
    int row  = gt >> 6;
    int lane = gt & 63;
    int lbl  = labels[row];
    const float4* xi = reinterpret_cast<const float4*>(inputs + (size_t)row * DIM);
    const float4* wi = reinterpret_cast<const float4*>(W + (size_t)lbl * DIM);
    float dot = 0.f;
    #pragma unroll
    for (int j = 0; j < 2; ++j) {
        float4 a = xi[lane + j * 64];
        float4 b = wi[lane + j * 64];
        dot += a.x * b.x + a.y * b.y + a.z * b.z + a.w * b.w;
    }
    #pragma unroll
    for (int off = 32; off; off >>= 1) dot += __shfl_down(dot, off, 64);
    if (lane == 0) {
        float tl = dot + bias[lbl] + neg_log_expected(lbl);
        true_logit[row] = tl;
        row_sum[row]    = expf(tl);
    }
}

// ---- kernel 4: 8192x8192x512 bf16 GEMM + exp/mask/row-sum epilogue ----------
// 128x128 tile, BK=32, 4 waves (2x2). T2 granule XOR-swizzle (both-sides:
// pre-swizzled global src for global_load_lds + swizzled ds_read addr).
// T4 counted vmcnt: 3-deep LDS pipeline, raw s_barrier, vmcnt(4) in loop.
__global__ __launch_bounds__(256) void k_gemm(
    const __hip_bfloat16* __restrict__ A, const __hip_bfloat16* __restrict__ B,
    const float* __restrict__ adj, const int* __restrict__ labels,
    const int* __restrict__ sampled, float* __restrict__ row_sum) {
    __shared__ alignas(16) __hip_bfloat16 Asm[3][128 * 32];
    __shared__ alignas(16) __hip_bfloat16 Bsm[3][128 * 32];
    __shared__ float tsum[2][128];

    const int tid  = threadIdx.x;
    const int wave = tid >> 6;
    const int lane = tid & 63;
    const int wr   = wave >> 1;
    const int wc   = wave & 1;

    // XCD-bijective swizzle (nwg = 4096, 4096 % 8 == 0)
    int bid = blockIdx.x;
    int wg  = (bid & 7) * 512 + (bid >> 3);
    const int brow = (wg >> 6) * 128;
    const int bcol = (wg & 63) * 128;

    // Staging geometry: lane l covers LDS row (l>>2), phys granule (l&3) of a
    // 16-row chunk. Swizzle f(row) = (row>>1)&3; fetch logical granule
    // (l&3) ^ f so that phys slot p holds logical granule p ^ f(row).
    const int srow = lane >> 2;                       // row within 16-row chunk
    const int sg   = (lane & 3) ^ ((lane >> 3) & 3);  // swizzled source granule

    f32x4 acc[4][4];
    #pragma unroll
    for (int m = 0; m < 4; ++m)
        #pragma unroll
        for (int n = 0; n < 4; ++n)
            acc[m][n] = (f32x4){0.f, 0.f, 0.f, 0.f};

    auto stage = [&](int buf, int kt) {
        #pragma unroll
        for (int i = 0; i < 2; ++i) {
            const __hip_bfloat16* gA =
                A + (size_t)(brow + wave * 32 + i * 16 + srow) * DIM + kt * 32 + sg * 8;
            gload_lds16(gA, &Asm[buf][(wave * 32 + i * 16) * 32]);
            const __hip_bfloat16* gB =
                B + (size_t)(bcol + wave * 32 + i * 16 + srow) * DIM + kt * 32 + sg * 8;
            gload_lds16(gB, &Bsm[buf][(wave * 32 + i * 16) * 32]);
        }
    };

    stage(0, 0);
    stage(1, 1);

    const int rsel = lane & 15;
    // Reader: logical granule = lane>>4, row = ...+rsel, phys = logical ^ f(row)
    const int koff = ((lane >> 4) ^ ((lane >> 1) & 3)) * 8;

    bf16x8 a[4], b[4];
    #pragma unroll 1
    for (int kt = 0; kt < 15; ++kt) {
        asm volatile("s_waitcnt vmcnt(4)" ::: "memory");   // stage kt complete
        asm volatile("s_barrier" ::: "memory");            // all waves staged kt
        const int cur = kt % 3;
        #pragma unroll
        for (int m = 0; m < 4; ++m)
            a[m] = *reinterpret_cast<const bf16x8*>(
                &Asm[cur][(wr * 64 + m * 16 + rsel) * 32 + koff]);
        #pragma unroll
        for (int n = 0; n < 4; ++n)
            b[n] = *reinterpret_cast<const bf16x8*>(
                &Bsm[cur][(wc * 64 + n * 16 + rsel) * 32 + koff]);
        if (kt < 14) stage((kt + 2) % 3, kt + 2);
        #pragma unroll
        for (int m = 0; m < 4; ++m)
            #pragma unroll
            for (int n = 0; n < 4; ++n)
                acc[m][n] = __builtin_amdgcn_mfma_f32_16x16x32_bf16(a[m], b[n], acc[m][n], 0, 0, 0);
    }
    // peeled last K-step (kt = 15, buffer 0)
    {
        asm volatile("s_waitcnt vmcnt(0)" ::: "memory");
        asm volatile("s_barrier" ::: "memory");
        #pragma unroll
        for (int m = 0; m < 4; ++m)
            a[m] = *reinterpret_cast<const bf16x8*>(
                &Asm[0][(wr * 64 + m * 16 + rsel) * 32 + koff]);
        #pragma unroll
        for (int n = 0; n < 4; ++n)
            b[n] = *reinterpret_cast<const bf16x8*>(
                &Bsm[0][(wc * 64 + n * 16 + rsel) * 32 + koff]);
        #pragma unroll
        for (int m = 0; m < 4; ++m)
            #pragma unroll
            for (int n = 0; n < 4; ++n)
                acc[m][n] = __builtin_amdgcn_mfma_f32_16x16x32_bf16(a[m], b[n], acc[m][n], 0, 0, 0);
    }

    // Epilogue: logit = acc + adj[col]; mask label==sampled; exp; per-row sum.
    int gcol[4]; float aadj[4]; int sval[4];
    #pragma unroll
    for (int n = 0; n < 4; ++n) {
        gcol[n] = bcol + wc * 64 + n * 16 + rsel;
        aadj[n] = adj[gcol[n]];
        sval[n] = sampled[gcol[n]];
    }
    #pragma unroll
    for (int m = 0; m < 4; ++m) {
        #pragma unroll
        for (int r = 0; r < 4; ++r) {
            int lr  = wr * 64 + m * 16 + (lane >> 4) * 4 + r;   // local row 0..127
            int lbl = labels[brow + lr];
            float part = 0.f;
            #pragma unroll
            for (int n = 0; n < 4; ++n) {
                float logit = acc[m][n][r] + aadj[n];
                part += (sval[n] == lbl) ? 0.f : __expf(logit);
            }
            part += __shfl_xor(part, 1, 16);
            part += __shfl_xor(part, 2, 16);
            part += __shfl_xor(part, 4, 16);
            part += __shfl_xor(part, 8, 16);
            if (rsel == 0) tsum[wc][lr] = part;   // one writer per (wc, lr)
        }
    }
    __syncthreads();
    if (tid < 128) atomicAdd(&row_sum[brow + tid], tsum[0][tid] + tsum[1][tid]);
}

// ---- kernel 5: loss = log(row_sum) - true_logit -----------------------------
__global__ void k_final(const float* __restrict__ row_sum,
                        const float* __restrict__ true_logit,
                        float* __restrict__ loss) {
    int i = blockIdx.x * blockDim.x + threadIdx.x;
    loss[i] = logf(row_sum[i]) - true_logit[i];
}

extern "C" void kernel_launch(void* const* d_in, const int* in_sizes, int n_in,
                              void* d_out, int out_size, void* d_ws, size_t ws_size,
                              hipStream_t stream) {
    const float* inputs  = (const float*)d_in[0];
    const int*   labels  = (const int*)d_in[1];
    const float* W       = (const float*)d_in[2];
    const float* bias    = (const float*)d_in[3];
    const int*   sampled = (const int*)d_in[4];
    float*       loss    = (float*)d_out;

    char* ws = (char*)d_ws;
    __hip_bfloat16* Abf = (__hip_bfloat16*)ws;                                  // 8 MiB
    __hip_bfloat16* Bbf = (__hip_bfloat16*)(ws + (size_t)BATCH * DIM * 2);      // 8 MiB
    float* adj        = (float*)(ws + (size_t)(BATCH + NSAMP) * DIM * 2);       // 32 KiB
    float* true_logit = adj + NSAMP;                                            // 32 KiB
    float* row_sum    = true_logit + BATCH;                                     // 32 KiB

    hipLaunchKernelGGL(k_convert, dim3((BATCH * DIM / 4) / 256), dim3(256), 0, stream,
                       inputs, Abf);
    hipLaunchKernelGGL(k_gather, dim3(NSAMP), dim3(128), 0, stream,
                       W, bias, sampled, Bbf, adj);
    hipLaunchKernelGGL(k_true, dim3(BATCH / 4), dim3(256), 0, stream,
                       inputs, labels, W, bias, true_logit, row_sum);
    hipLaunchKernelGGL(k_gemm, dim3((BATCH / 128) * (NSAMP / 128)), dim3(256), 0, stream,
                       Abf, Bbf, adj, labels, sampled, row_sum);
    hipLaunchKernelGGL(k_final, dim3(BATCH / 256), dim3(256), 0, stream,
                       row_sum, true_logit, loss);
}

// Round 3
// 134.322 us; speedup vs baseline: 1.4484x; 1.0966x over previous
//
#include <hip/hip_runtime.h>
#include <hip/hip_bf16.h>
#include <cstdint>
#include <cstddef>

#define BATCH   8192
#define NSAMP   8192
#define DIM     512
#define NCLASS  50000

typedef __attribute__((ext_vector_type(8))) short bf16x8;
typedef __attribute__((ext_vector_type(4))) float f32x4;

// -log(expected_count(c)) for the log-uniform sampler, in double to match the
// numpy reference (f32 log(c+2)-log(c+1) catastrophically cancels at large c).
__device__ __forceinline__ float neg_log_expected(int c) {
    double p = log1p(1.0 / (double)(c + 1)) / log((double)(NCLASS + 1));
    double e = -expm1((double)NSAMP * log1p(-p));
    return (float)(-log(e));
}

__device__ __forceinline__ unsigned short f2bf(float f) {
    __hip_bfloat16 h = __float2bfloat16(f);
    return *reinterpret_cast<unsigned short*>(&h);
}

__device__ __forceinline__ void gload_lds16(const void* g, void* l) {
    __builtin_amdgcn_global_load_lds(
        (const __attribute__((address_space(1))) void*)g,
        (__attribute__((address_space(3))) void*)l, 16, 0, 0);
}

// ---- kernel 1: fused inputs f32->bf16 + true-logit + row_sum seed ----------
// One block per row (128 threads): convert the row to bf16 for the GEMM A
// matrix AND compute dot(inputs[row], W[label[row]]) in the same pass.
__global__ void k_fused(const float* __restrict__ inputs, const int* __restrict__ labels,
                        const float* __restrict__ W, const float* __restrict__ bias,
                        __hip_bfloat16* __restrict__ Abf,
                        float* __restrict__ true_logit, float* __restrict__ row_sum) {
    int row = blockIdx.x;
    int t   = threadIdx.x;                       // 0..127
    float4 v = reinterpret_cast<const float4*>(inputs + (size_t)row * DIM)[t];
    ushort4 u;
    u.x = f2bf(v.x); u.y = f2bf(v.y); u.z = f2bf(v.z); u.w = f2bf(v.w);
    reinterpret_cast<ushort4*>(Abf + (size_t)row * DIM)[t] = u;

    int lbl = labels[row];
    float4 w = reinterpret_cast<const float4*>(W + (size_t)lbl * DIM)[t];
    float dot = v.x * w.x + v.y * w.y + v.z * w.z + v.w * w.w;
    #pragma unroll
    for (int off = 32; off; off >>= 1) dot += __shfl_down(dot, off, 64);
    __shared__ float red[2];
    if ((t & 63) == 0) red[t >> 6] = dot;
    __syncthreads();
    if (t == 0) {
        float tl = red[0] + red[1] + bias[lbl] + neg_log_expected(lbl);
        true_logit[row] = tl;
        row_sum[row]    = __expf(tl);
    }
}

// ---- kernel 2: gather kernel[sampled] -> bf16 B; adj[s] = bias - log(expected)
__global__ void k_gather(const float* __restrict__ W, const float* __restrict__ bias,
                         const int* __restrict__ sampled,
                         __hip_bfloat16* __restrict__ Bbf, float* __restrict__ adj) {
    int s   = blockIdx.x;
    int idx = sampled[s];
    float4 v = reinterpret_cast<const float4*>(W + (size_t)idx * DIM)[threadIdx.x];
    ushort4 u;
    u.x = f2bf(v.x); u.y = f2bf(v.y); u.z = f2bf(v.z); u.w = f2bf(v.w);
    reinterpret_cast<ushort4*>(Bbf + (size_t)s * DIM)[threadIdx.x] = u;
    if (threadIdx.x == 0) adj[s] = bias[idx] + neg_log_expected(idx);
}

// ---- kernel 3: 8192x8192x512 bf16 GEMM, 256^2 8-phase structure ------------
// BM=BN=256, BK=64, 8 waves (2M x 4N), 512 threads, LDS 128KB 2-dbuf.
// T2: involutive granule XOR swizzle (pre-swizzled global src + swizzled
//     ds_read addr), 2-way residual conflict = free.
// T3/T4: one half-tile staged per phase, deadline-ordered, counted vmcnt(6),
//     never drained mid-loop. T5: setprio around each 16-MFMA cluster.
// Epilogue: logit=acc+adj[col]; mask label==sampled; exp; per-row sum ->
//     LDS combine across the 4 col-waves -> one atomicAdd per row.

#define BARRIER() asm volatile("s_barrier" ::: "memory")
#define VMCNT(n)  asm volatile("s_waitcnt vmcnt(" #n ")" ::: "memory")

#define READ_A(BUF, MH)                                                        \
    _Pragma("unroll")                                                          \
    for (int mi = 0; mi < 4; ++mi)                                             \
      _Pragma("unroll")                                                        \
      for (int ks = 0; ks < 2; ++ks)                                           \
        af[mi][ks] = *reinterpret_cast<const bf16x8*>(                         \
          &Asm[BUF][abase + ((MH)*4 + mi)*2048 + (((ks*4) + gg) ^ axg)*8]);

#define READ_B(BUF, NH)                                                        \
    _Pragma("unroll")                                                          \
    for (int ni = 0; ni < 2; ++ni)                                             \
      _Pragma("unroll")                                                        \
      for (int ks = 0; ks < 2; ++ks)                                           \
        bfr[ni][ks] = *reinterpret_cast<const bf16x8*>(                        \
          &Bsm[BUF][bbase + ((NH)*2 + ni)*4096 + (((ks*4) + gg) ^ axg)*8]);

#define MFMA_Q(MH, NH)                                                         \
    __builtin_amdgcn_s_setprio(1);                                             \
    _Pragma("unroll")                                                          \
    for (int mi = 0; mi < 4; ++mi)                                             \
      _Pragma("unroll")                                                        \
      for (int ni = 0; ni < 2; ++ni)                                           \
        _Pragma("unroll")                                                      \
        for (int ks = 0; ks < 2; ++ks)                                         \
          acc[(MH)*4+mi][(NH)*2+ni] = __builtin_amdgcn_mfma_f32_16x16x32_bf16( \
            af[mi][ks], bfr[ni][ks], acc[(MH)*4+mi][(NH)*2+ni], 0, 0, 0);      \
    __builtin_amdgcn_s_setprio(0);

__global__ __launch_bounds__(512, 1) void k_gemm(
    const __hip_bfloat16* __restrict__ A, const __hip_bfloat16* __restrict__ B,
    const float* __restrict__ adj, const int* __restrict__ labels,
    const int* __restrict__ sampled, float* __restrict__ row_sum) {
    __shared__ alignas(16) __hip_bfloat16 Asm[2][256 * 64];   // 64 KiB
    __shared__ alignas(16) __hip_bfloat16 Bsm[2][256 * 64];   // 64 KiB
    __shared__ float tsum[4][256];                            // 4 KiB

    const int tid  = threadIdx.x;
    const int wave = tid >> 6;
    const int lane = tid & 63;
    const int wr   = wave >> 2;          // 0..1  (M half, interleaved by 16)
    const int wc   = wave & 3;           // 0..3  (N quarter, interleaved by 16)

    // XCD-bijective swizzle (nwg = 1024, 1024 % 8 == 0)
    int bid = blockIdx.x;
    int wg  = (bid & 7) * 128 + (bid >> 3);
    const int brow = (wg >> 5) * 256;
    const int bcol = (wg & 31) * 256;

    // staging: lane covers row (l>>3) of an 8-row wave chunk, phys granule l&7;
    // fetch logical granule (l&7)^f(row), f(row)=row&7 (involution, both-sides)
    const int sr8 = lane >> 3;
    const int sg8 = (lane & 7) ^ sr8;

    // fragment read: row = m*32 + wr*16 + rsel; phys granule = logical ^ (rsel&7)
    const int rsel  = lane & 15;
    const int gg    = lane >> 4;
    const int axg   = rsel & 7;
    const int abase = (wr * 16 + rsel) * 64;
    const int bbase = (wc * 16 + rsel) * 64;

    f32x4 acc[8][4];
    #pragma unroll
    for (int m = 0; m < 8; ++m)
        #pragma unroll
        for (int n = 0; n < 4; ++n)
            acc[m][n] = (f32x4){0.f, 0.f, 0.f, 0.f};

    auto stageA = [&](int buf, int kt, int half) {
        #pragma unroll
        for (int i = 0; i < 2; ++i) {
            const int lrow = half * 128 + i * 64 + wave * 8;   // wave-uniform
            const __hip_bfloat16* g =
                A + (size_t)(brow + lrow + sr8) * DIM + kt * 64 + sg8 * 8;
            gload_lds16(g, &Asm[buf][lrow * 64]);
        }
    };
    auto stageB = [&](int buf, int kt, int half) {
        #pragma unroll
        for (int i = 0; i < 2; ++i) {
            const int lrow = half * 128 + i * 64 + wave * 8;
            const __hip_bfloat16* g =
                B + (size_t)(bcol + lrow + sr8) * DIM + kt * 64 + sg8 * 8;
            gload_lds16(g, &Bsm[buf][lrow * 64]);
        }
    };

    // prologue: tile 0's four halves, deadline order
    stageA(0, 0, 0); stageB(0, 0, 0); stageA(0, 0, 1); stageB(0, 0, 1);

    bf16x8 af[4][2], bfr[2][2];

    #pragma unroll 1
    for (int t = 0; t < 7; ++t) {
        const int buf = t & 1, nb = buf ^ 1, nt = t + 1;
        // phase 0: (mh0, nh0)
        stageA(nb, nt, 0); VMCNT(6); BARRIER();
        READ_A(buf, 0); READ_B(buf, 0); MFMA_Q(0, 0);
        // phase 1: (mh1, nh0) — B held in regs
        stageB(nb, nt, 0); VMCNT(6); BARRIER();
        READ_A(buf, 1); MFMA_Q(1, 0);
        // phase 2: (mh1, nh1) — A held in regs
        stageA(nb, nt, 1); VMCNT(6); BARRIER();
        READ_B(buf, 1); MFMA_Q(1, 1);
        // phase 3: (mh0, nh1) — no new half needed, no wait
        stageB(nb, nt, 1);
        READ_A(buf, 0); MFMA_Q(0, 1);
        BARRIER();   // tile-closing: reads of buf done before next tile's stages
    }
    // peeled last tile (t = 7, buf = 1): drain 4 -> 2 -> 0
    {
        VMCNT(4); BARRIER();
        READ_A(1, 0); READ_B(1, 0); MFMA_Q(0, 0);
        VMCNT(2); BARRIER();
        READ_A(1, 1); MFMA_Q(1, 0);
        VMCNT(0); BARRIER();
        READ_B(1, 1); MFMA_Q(1, 1);
        READ_A(1, 0); MFMA_Q(0, 1);
    }

    // ---- epilogue ----------------------------------------------------------
    int sv[4]; float aadj[4];
    #pragma unroll
    for (int n = 0; n < 4; ++n) {
        int col = bcol + n * 64 + wc * 16 + rsel;
        aadj[n] = adj[col];
        sv[n]   = sampled[col];
    }
    #pragma unroll
    for (int m = 0; m < 8; ++m) {
        #pragma unroll
        for (int r = 0; r < 4; ++r) {
            int lrow = m * 32 + wr * 16 + gg * 4 + r;
            int lbl  = labels[brow + lrow];
            float part = 0.f;
            #pragma unroll
            for (int n = 0; n < 4; ++n) {
                float logit = acc[m][n][r] + aadj[n];
                part += (sv[n] == lbl) ? 0.f : __expf(logit);
            }
            part += __shfl_xor(part, 1, 16);
            part += __shfl_xor(part, 2, 16);
            part += __shfl_xor(part, 4, 16);
            part += __shfl_xor(part, 8, 16);
            if (rsel == 0) tsum[wc][lrow] = part;
        }
    }
    __syncthreads();
    if (tid < 256)
        atomicAdd(&row_sum[brow + tid],
                  tsum[0][tid] + tsum[1][tid] + tsum[2][tid] + tsum[3][tid]);
}

// ---- kernel 4: loss = log(row_sum) - true_logit -----------------------------
__global__ void k_final(const float* __restrict__ row_sum,
                        const float* __restrict__ true_logit,
                        float* __restrict__ loss) {
    int i = blockIdx.x * blockDim.x + threadIdx.x;
    loss[i] = logf(row_sum[i]) - true_logit[i];
}

extern "C" void kernel_launch(void* const* d_in, const int* in_sizes, int n_in,
                              void* d_out, int out_size, void* d_ws, size_t ws_size,
                              hipStream_t stream) {
    const float* inputs  = (const float*)d_in[0];
    const int*   labels  = (const int*)d_in[1];
    const float* W       = (const float*)d_in[2];
    const float* bias    = (const float*)d_in[3];
    const int*   sampled = (const int*)d_in[4];
    float*       loss    = (float*)d_out;

    char* ws = (char*)d_ws;
    __hip_bfloat16* Abf = (__hip_bfloat16*)ws;                                  // 8 MiB
    __hip_bfloat16* Bbf = (__hip_bfloat16*)(ws + (size_t)BATCH * DIM * 2);      // 8 MiB
    float* adj        = (float*)(ws + (size_t)(BATCH + NSAMP) * DIM * 2);       // 32 KiB
    float* true_logit = adj + NSAMP;                                            // 32 KiB
    float* row_sum    = true_logit + BATCH;                                     // 32 KiB

    hipLaunchKernelGGL(k_fused, dim3(BATCH), dim3(128), 0, stream,
                       inputs, labels, W, bias, Abf, true_logit, row_sum);
    hipLaunchKernelGGL(k_gather, dim3(NSAMP), dim3(128), 0, stream,
                       W, bias, sampled, Bbf, adj);
    hipLaunchKernelGGL(k_gemm, dim3((BATCH / 256) * (NSAMP / 256)), dim3(512), 0, stream,
                       Abf, Bbf, adj, labels, sampled, row_sum);
    hipLaunchKernelGGL(k_final, dim3(BATCH / 256), dim3(256), 0, stream,
                       row_sum, true_logit, loss);
}

// Round 4
// 120.111 us; speedup vs baseline: 1.6198x; 1.1183x over previous
//
#include <hip/hip_runtime.h>
#include <hip/hip_bf16.h>
#include <cstdint>
#include <cstddef>

#define BATCH   8192
#define NSAMP   8192
#define DIM     512
#define NCLASS  50000

typedef __attribute__((ext_vector_type(8))) short bf16x8;
typedef __attribute__((ext_vector_type(4))) float f32x4;

// -log(expected_count(c)) for the log-uniform sampler, in double to match the
// numpy reference (f32 log(c+2)-log(c+1) catastrophically cancels at large c).
__device__ __forceinline__ float neg_log_expected(int c) {
    double p = log1p(1.0 / (double)(c + 1)) / log((double)(NCLASS + 1));
    double e = -expm1((double)NSAMP * log1p(-p));
    return (float)(-log(e));
}

__device__ __forceinline__ unsigned short f2bf(float f) {
    __hip_bfloat16 h = __float2bfloat16(f);
    return *reinterpret_cast<unsigned short*>(&h);
}

__device__ __forceinline__ void gload_lds16(const void* g, void* l) {
    __builtin_amdgcn_global_load_lds(
        (const __attribute__((address_space(1))) void*)g,
        (__attribute__((address_space(3))) void*)l, 16, 0, 0);
}

// ---- kernel 1: fused inputs f32->bf16 + true-logit + row_sum seed ----------
__global__ void k_fused(const float* __restrict__ inputs, const int* __restrict__ labels,
                        const float* __restrict__ W, const float* __restrict__ bias,
                        __hip_bfloat16* __restrict__ Abf,
                        float* __restrict__ true_logit, float* __restrict__ row_sum) {
    int row = blockIdx.x;
    int t   = threadIdx.x;                       // 0..127
    float4 v = reinterpret_cast<const float4*>(inputs + (size_t)row * DIM)[t];
    ushort4 u;
    u.x = f2bf(v.x); u.y = f2bf(v.y); u.z = f2bf(v.z); u.w = f2bf(v.w);
    reinterpret_cast<ushort4*>(Abf + (size_t)row * DIM)[t] = u;

    int lbl = labels[row];
    float4 w = reinterpret_cast<const float4*>(W + (size_t)lbl * DIM)[t];
    float dot = v.x * w.x + v.y * w.y + v.z * w.z + v.w * w.w;
    #pragma unroll
    for (int off = 32; off; off >>= 1) dot += __shfl_down(dot, off, 64);
    __shared__ float red[2];
    if ((t & 63) == 0) red[t >> 6] = dot;
    __syncthreads();
    if (t == 0) {
        float tl = red[0] + red[1] + bias[lbl] + neg_log_expected(lbl);
        true_logit[row] = tl;
        row_sum[row]    = __expf(tl);
    }
}

// ---- kernel 2: gather kernel[sampled] -> bf16 B; adj[s] = bias - log(expected)
__global__ void k_gather(const float* __restrict__ W, const float* __restrict__ bias,
                         const int* __restrict__ sampled,
                         __hip_bfloat16* __restrict__ Bbf, float* __restrict__ adj) {
    int s   = blockIdx.x;
    int idx = sampled[s];
    float4 v = reinterpret_cast<const float4*>(W + (size_t)idx * DIM)[threadIdx.x];
    ushort4 u;
    u.x = f2bf(v.x); u.y = f2bf(v.y); u.z = f2bf(v.z); u.w = f2bf(v.w);
    reinterpret_cast<ushort4*>(Bbf + (size_t)s * DIM)[threadIdx.x] = u;
    if (threadIdx.x == 0) adj[s] = bias[idx] + neg_log_expected(idx);
}

// ---- kernel 3: 8192x8192x512 bf16 GEMM, 256^2 structure --------------------
// BM=BN=256, BK=64, 8 waves (2M x 4N), 512 threads, LDS 128KB 2-dbuf.
// T2 involutive granule swizzle; T4 counted vmcnt(6); T5 setprio.
// Round-3 changes vs round-2:
//  (a) 2D XCD-local rasterization: per-XCD concurrent working set = 8 A-panels
//      (2MB, L2-resident across all rounds) + 4 B-panels (1MB/round) = 3MB
//      <= 4MB L2  -> staging hits L2 (~200cy), covered by the 4-phase lead.
//  (b) no snake re-read: both B half-tiles held in regs (bf0, bf1); quadrant
//      order (0,0)->(0,1)->(1,1)->(1,0); 24 ds_read_b128/wave/tile (was 32).

#define BARRIER() asm volatile("s_barrier" ::: "memory")
#define VMCNT(n)  asm volatile("s_waitcnt vmcnt(" #n ")" ::: "memory")

#define READ_A(BUF, MH)                                                        \
    _Pragma("unroll")                                                          \
    for (int mi = 0; mi < 4; ++mi)                                             \
      _Pragma("unroll")                                                        \
      for (int ks = 0; ks < 2; ++ks)                                           \
        af[mi][ks] = *reinterpret_cast<const bf16x8*>(                         \
          &Asm[BUF][abase + ((MH)*4 + mi)*2048 + (((ks*4) + gg) ^ axg)*8]);

#define READ_B(BUF, NH, DST)                                                   \
    _Pragma("unroll")                                                          \
    for (int ni = 0; ni < 2; ++ni)                                             \
      _Pragma("unroll")                                                        \
      for (int ks = 0; ks < 2; ++ks)                                           \
        DST[ni][ks] = *reinterpret_cast<const bf16x8*>(                        \
          &Bsm[BUF][bbase + ((NH)*2 + ni)*4096 + (((ks*4) + gg) ^ axg)*8]);

#define MFMA_Q(MH, NH, BSRC)                                                   \
    __builtin_amdgcn_s_setprio(1);                                             \
    _Pragma("unroll")                                                          \
    for (int mi = 0; mi < 4; ++mi)                                             \
      _Pragma("unroll")                                                        \
      for (int ni = 0; ni < 2; ++ni)                                           \
        _Pragma("unroll")                                                      \
        for (int ks = 0; ks < 2; ++ks)                                         \
          acc[(MH)*4+mi][(NH)*2+ni] = __builtin_amdgcn_mfma_f32_16x16x32_bf16( \
            af[mi][ks], BSRC[ni][ks], acc[(MH)*4+mi][(NH)*2+ni], 0, 0, 0);     \
    __builtin_amdgcn_s_setprio(0);

__global__ __launch_bounds__(512, 1) void k_gemm(
    const __hip_bfloat16* __restrict__ A, const __hip_bfloat16* __restrict__ B,
    const float* __restrict__ adj, const int* __restrict__ labels,
    const int* __restrict__ sampled, float* __restrict__ row_sum) {
    __shared__ alignas(16) __hip_bfloat16 Asm[2][256 * 64];   // 64 KiB
    __shared__ alignas(16) __hip_bfloat16 Bsm[2][256 * 64];   // 64 KiB
    __shared__ float tsum[4][256];                            // 4 KiB

    const int tid  = threadIdx.x;
    const int wave = tid >> 6;
    const int lane = tid & 63;
    const int wr   = wave >> 2;          // 0..1  (M half)
    const int wc   = wave & 3;           // 0..3  (N quarter)

    // 2D XCD-local rasterization (bijective, hand-verified):
    //   xcd = bid&7, round = bid>>8, w = (bid>>3)&31
    //   trow = (xcd&3)*8 + (w>>2)   in [0,32)
    //   tcol = round*8 + (xcd>>2)*4 + (w&3)  in [0,32)
    const int bid   = blockIdx.x;
    const int xcd   = bid & 7;
    const int w     = (bid >> 3) & 31;
    const int rnd   = bid >> 8;
    const int brow  = ((xcd & 3) * 8 + (w >> 2)) * 256;
    const int bcol  = (rnd * 8 + (xcd >> 2) * 4 + (w & 3)) * 256;

    // staging: lane covers row (l>>3) of an 8-row wave chunk, phys granule l&7;
    // fetch logical granule (l&7)^row (involution, both-sides)
    const int sr8 = lane >> 3;
    const int sg8 = (lane & 7) ^ sr8;

    // fragment read: row = frag*32 + wr*16 + rsel; phys granule = logical^(rsel&7)
    const int rsel  = lane & 15;
    const int gg    = lane >> 4;
    const int axg   = rsel & 7;
    const int abase = (wr * 16 + rsel) * 64;
    const int bbase = (wc * 16 + rsel) * 64;

    f32x4 acc[8][4];
    #pragma unroll
    for (int m = 0; m < 8; ++m)
        #pragma unroll
        for (int n = 0; n < 4; ++n)
            acc[m][n] = (f32x4){0.f, 0.f, 0.f, 0.f};

    auto stageA = [&](int buf, int kt, int half) {
        #pragma unroll
        for (int i = 0; i < 2; ++i) {
            const int lrow = half * 128 + i * 64 + wave * 8;   // wave-uniform
            const __hip_bfloat16* g =
                A + (size_t)(brow + lrow + sr8) * DIM + kt * 64 + sg8 * 8;
            gload_lds16(g, &Asm[buf][lrow * 64]);
        }
    };
    auto stageB = [&](int buf, int kt, int half) {
        #pragma unroll
        for (int i = 0; i < 2; ++i) {
            const int lrow = half * 128 + i * 64 + wave * 8;
            const __hip_bfloat16* g =
                B + (size_t)(bcol + lrow + sr8) * DIM + kt * 64 + sg8 * 8;
            gload_lds16(g, &Bsm[buf][lrow * 64]);
        }
    };

    // prologue: tile 0, issue order = consumption order (Ah0, Bh0, Bh1, Ah1)
    stageA(0, 0, 0); stageB(0, 0, 0); stageB(0, 0, 1); stageA(0, 0, 1);

    bf16x8 af[4][2], bf0[2][2], bf1[2][2];

    #pragma unroll 1
    for (int t = 0; t < 7; ++t) {
        const int buf = t & 1, nb = buf ^ 1, nt = t + 1;
        // phase 0: quadrant (0,0) — consumes Ah0+Bh0
        stageA(nb, nt, 0); VMCNT(6); BARRIER();
        READ_A(buf, 0); READ_B(buf, 0, bf0); MFMA_Q(0, 0, bf0);
        // phase 1: quadrant (0,1) — consumes Bh1 (A h0 held)
        stageB(nb, nt, 0); VMCNT(6); BARRIER();
        READ_B(buf, 1, bf1); MFMA_Q(0, 1, bf1);
        // phase 2: quadrant (1,1) — consumes Ah1 (B h1 held)
        stageB(nb, nt, 1); VMCNT(6); BARRIER();
        READ_A(buf, 1); MFMA_Q(1, 1, bf1);
        // phase 3: quadrant (1,0) — all operands held in regs
        stageA(nb, nt, 1);
        MFMA_Q(1, 0, bf0);
        BARRIER();   // closing: all reads of buf done before next tile stages it
    }
    // peeled last tile (t = 7, buf = 1): drain 4 -> 2 -> 0
    {
        VMCNT(4); BARRIER();
        READ_A(1, 0); READ_B(1, 0, bf0); MFMA_Q(0, 0, bf0);
        VMCNT(2); BARRIER();
        READ_B(1, 1, bf1); MFMA_Q(0, 1, bf1);
        VMCNT(0); BARRIER();
        READ_A(1, 1); MFMA_Q(1, 1, bf1);
        MFMA_Q(1, 0, bf0);
    }

    // ---- epilogue ----------------------------------------------------------
    int sv[4]; float aadj[4];
    #pragma unroll
    for (int n = 0; n < 4; ++n) {
        int col = bcol + n * 64 + wc * 16 + rsel;
        aadj[n] = adj[col];
        sv[n]   = sampled[col];
    }
    #pragma unroll
    for (int m = 0; m < 8; ++m) {
        #pragma unroll
        for (int r = 0; r < 4; ++r) {
            int lrow = m * 32 + wr * 16 + gg * 4 + r;
            int lbl  = labels[brow + lrow];
            float part = 0.f;
            #pragma unroll
            for (int n = 0; n < 4; ++n) {
                float logit = acc[m][n][r] + aadj[n];
                part += (sv[n] == lbl) ? 0.f : __expf(logit);
            }
            part += __shfl_xor(part, 1, 16);
            part += __shfl_xor(part, 2, 16);
            part += __shfl_xor(part, 4, 16);
            part += __shfl_xor(part, 8, 16);
            if (rsel == 0) tsum[wc][lrow] = part;
        }
    }
    __syncthreads();
    if (tid < 256)
        atomicAdd(&row_sum[brow + tid],
                  tsum[0][tid] + tsum[1][tid] + tsum[2][tid] + tsum[3][tid]);
}

// ---- kernel 4: loss = log(row_sum) - true_logit -----------------------------
__global__ void k_final(const float* __restrict__ row_sum,
                        const float* __restrict__ true_logit,
                        float* __restrict__ loss) {
    int i = blockIdx.x * blockDim.x + threadIdx.x;
    loss[i] = logf(row_sum[i]) - true_logit[i];
}

extern "C" void kernel_launch(void* const* d_in, const int* in_sizes, int n_in,
                              void* d_out, int out_size, void* d_ws, size_t ws_size,
                              hipStream_t stream) {
    const float* inputs  = (const float*)d_in[0];
    const int*   labels  = (const int*)d_in[1];
    const float* W       = (const float*)d_in[2];
    const float* bias    = (const float*)d_in[3];
    const int*   sampled = (const int*)d_in[4];
    float*       loss    = (float*)d_out;

    char* ws = (char*)d_ws;
    __hip_bfloat16* Abf = (__hip_bfloat16*)ws;                                  // 8 MiB
    __hip_bfloat16* Bbf = (__hip_bfloat16*)(ws + (size_t)BATCH * DIM * 2);      // 8 MiB
    float* adj        = (float*)(ws + (size_t)(BATCH + NSAMP) * DIM * 2);       // 32 KiB
    float* true_logit = adj + NSAMP;                                            // 32 KiB
    float* row_sum    = true_logit + BATCH;                                     // 32 KiB

    hipLaunchKernelGGL(k_fused, dim3(BATCH), dim3(128), 0, stream,
                       inputs, labels, W, bias, Abf, true_logit, row_sum);
    hipLaunchKernelGGL(k_gather, dim3(NSAMP), dim3(128), 0, stream,
                       W, bias, sampled, Bbf, adj);
    hipLaunchKernelGGL(k_gemm, dim3((BATCH / 256) * (NSAMP / 256)), dim3(512), 0, stream,
                       Abf, Bbf, adj, labels, sampled, row_sum);
    hipLaunchKernelGGL(k_final, dim3(BATCH / 256), dim3(256), 0, stream,
                       row_sum, true_logit, loss);
}